// Round 2
// baseline (131.403 us; speedup 1.0000x reference)
//
#include <hip/hip_runtime.h>
#include <math.h>

#define MM 8
#define SS 4
#define NLEAF 20
#define KINT 19
#define NBR 38                   // total branches: 2 + 18*2
#define P4 (NBR*MM*4)            // float4 count of P region = 1216
#define PFLOATS (P4*4)           // 4864 floats
#define NNODE 39

typedef float v2f __attribute__((ext_vector_type(2)));
typedef float v4f __attribute__((ext_vector_type(4)));

// ---------------- setup: Q build + 304 small expm (fp64), stores P TRANSPOSED ----------------

__device__ __forceinline__ void mat4_mul(const double a[4][4], const double b[4][4], double c[4][4]) {
    #pragma unroll
    for (int i = 0; i < 4; i++)
        #pragma unroll
        for (int j = 0; j < 4; j++) {
            double s = 0.0;
            #pragma unroll
            for (int k = 0; k < 4; k++) s += a[i][k] * b[k][j];
            c[i][j] = s;
        }
}

__global__ void setup_kernel(const float* __restrict__ rates,
                             const float* __restrict__ pi_inv,
                             const float* __restrict__ rho,
                             const float* __restrict__ T,
                             float* __restrict__ ws)   // [NBR][MM][4][4] P^T, then pi[MM][4]
{
    int tid = blockIdx.x * blockDim.x + threadIdx.x;
    if (tid >= NBR * MM) return;
    int m = tid & 7;
    int k = tid >> 3;

    // pi = inv_stereographic_projection(pi_inv)^2
    double y0 = pi_inv[m*3+0], y1 = pi_inv[m*3+1], y2 = pi_inv[m*3+2];
    double ns  = y0*y0 + y1*y1 + y2*y2;
    double inv = 1.0 / (ns + 1.0);
    double p[4] = {2.0*y0*inv, 2.0*y1*inv, 2.0*y2*inv, (ns-1.0)*inv};
    #pragma unroll
    for (int i = 0; i < 4; i++) p[i] *= p[i];

    if (k == 0) {
        #pragma unroll
        for (int i = 0; i < 4; i++) ws[PFLOATS + m*4 + i] = (float)p[i];
    }

    // Q from squared rates
    double r[6];
    #pragma unroll
    for (int i = 0; i < 6; i++) { double v = rates[m*6+i]; r[i] = v*v; }
    double Q[4][4] = {};
    Q[0][1]=r[0]; Q[0][2]=r[1]; Q[0][3]=r[2]; Q[1][2]=r[3]; Q[1][3]=r[4]; Q[2][3]=r[5];
    #pragma unroll
    for (int i = 0; i < 4; i++)
        #pragma unroll
        for (int j = i+1; j < 4; j++) Q[j][i] = Q[i][j];
    #pragma unroll
    for (int i = 0; i < 4; i++)
        #pragma unroll
        for (int j = 0; j < 4; j++) Q[i][j] *= p[j];
    double emut = 0.0;
    #pragma unroll
    for (int i = 0; i < 4; i++) {
        double rs = 0.0;
        #pragma unroll
        for (int j = 0; j < 4; j++) if (j != i) rs += Q[i][j];
        Q[i][i] = -rs;
        emut += p[i] * rs;
    }
    emut = fmax(emut, 1e-9);
    double scq = (double)rho[m] / emut;

    // branch length for branch k (caterpillar)
    double t;
    if      (k == 0) t = T[0*NNODE + NLEAF];
    else if (k == 1) t = T[1*NNODE + NLEAF];
    else {
        int j     = k >> 1;                       // 1..18
        int node  = NLEAF + j;
        int child = (k & 1) ? (j + 1) : (NLEAF - 1 + j);
        t = T[child*NNODE + node];
    }

    double A[4][4];
    #pragma unroll
    for (int i = 0; i < 4; i++)
        #pragma unroll
        for (int j = 0; j < 4; j++) A[i][j] = Q[i][j] * scq * t;

    // expm: scale to norm <= 2^-4, Taylor(9), square back
    double nrm = 0.0;
    #pragma unroll
    for (int i = 0; i < 4; i++) {
        double rs = 0.0;
        #pragma unroll
        for (int j = 0; j < 4; j++) rs += fabs(A[i][j]);
        nrm = fmax(nrm, rs);
    }
    int s = 0;
    if (nrm > 0.0625) s = (int)ceil(log2(nrm * 16.0));
    if (s < 0) s = 0;
    if (s > 60) s = 60;
    double scl = ldexp(1.0, -s);
    double B[4][4];
    #pragma unroll
    for (int i = 0; i < 4; i++)
        #pragma unroll
        for (int j = 0; j < 4; j++) B[i][j] = A[i][j] * scl;

    double E[4][4];
    #pragma unroll
    for (int i = 0; i < 4; i++)
        #pragma unroll
        for (int j = 0; j < 4; j++) E[i][j] = (i == j) ? 1.0 : 0.0;
    for (int kk = 9; kk >= 1; --kk) {
        double Tm[4][4];
        mat4_mul(B, E, Tm);
        double ik = 1.0 / (double)kk;
        #pragma unroll
        for (int i = 0; i < 4; i++)
            #pragma unroll
            for (int j = 0; j < 4; j++) E[i][j] = ((i == j) ? 1.0 : 0.0) + Tm[i][j] * ik;
    }
    for (int q = 0; q < s; q++) {
        double Tm[4][4];
        mat4_mul(E, E, Tm);
        #pragma unroll
        for (int i = 0; i < 4; i++)
            #pragma unroll
            for (int j = 0; j < 4; j++) E[i][j] = Tm[i][j];
    }

    // TRANSPOSED store: Pout[d*4 + c] = E[c][d]  => float4 at offset d is column d of P
    float* Pout = ws + (k*MM + m) * 16;
    #pragma unroll
    for (int d = 0; d < 4; d++)
        #pragma unroll
        for (int c = 0; c < 4; c++) Pout[d*4+c] = (float)E[c][d];
}

// ---------------- main: 2 sites/thread, packed-fp32 math, P columns broadcast from LDS ----------------

// pair-accumulated 4x4 matvec: cols c0..c3 are columns of P; s0..s3 are splats of the
// operand vector elements. lo = {res0,res1}, hi = {res2,res3}.
__device__ __forceinline__ void dotc(v4f c0, v4f c1, v4f c2, v4f c3,
                                     v2f s0, v2f s1, v2f s2, v2f s3,
                                     v2f& lo, v2f& hi)
{
    v2f l = (v2f){c0.x, c0.y} * s0;
    v2f h = (v2f){c0.z, c0.w} * s0;
    l = __builtin_elementwise_fma((v2f){c1.x, c1.y}, s1, l);
    h = __builtin_elementwise_fma((v2f){c1.z, c1.w}, s1, h);
    l = __builtin_elementwise_fma((v2f){c2.x, c2.y}, s2, l);
    h = __builtin_elementwise_fma((v2f){c2.z, c2.w}, s2, h);
    l = __builtin_elementwise_fma((v2f){c3.x, c3.y}, s3, l);
    h = __builtin_elementwise_fma((v2f){c3.z, c3.w}, s3, h);
    lo = l; hi = h;
}

__global__ __launch_bounds__(128) void phylo_kernel(const float* __restrict__ X,
                                                    const float* __restrict__ ws,
                                                    float* __restrict__ out,
                                                    int batch)
{
    __shared__ v4f Pl[P4 + MM];
    const v4f* w4 = (const v4f*)ws;
    for (int idx = threadIdx.x; idx < P4 + MM; idx += 128) Pl[idx] = w4[idx];
    __syncthreads();

    const int t  = threadIdx.x;
    const int i0 = blockIdx.x * 256 + t;
    const int i1 = i0 + 128;
    const size_t b0 = (size_t)(i0 < batch ? i0 : batch - 1) * 20;  // site stride = 20 float4
    const size_t b1 = (size_t)(i1 < batch ? i1 : batch - 1) * 20;
    const v4f* X4 = (const v4f*)X;

    v2f alo[2][MM], ahi[2][MM];

    // ---- step 0: node 20 = (leaf0, leaf1) ----
    {
        v4f x00 = X4[b0+0], x01 = X4[b0+1];
        v4f x10 = X4[b1+0], x11 = X4[b1+1];
        v2f sA0={x00.x,x00.x}, sA1={x00.y,x00.y}, sA2={x00.z,x00.z}, sA3={x00.w,x00.w};
        v2f sB0={x01.x,x01.x}, sB1={x01.y,x01.y}, sB2={x01.z,x01.z}, sB3={x01.w,x01.w};
        v2f sC0={x10.x,x10.x}, sC1={x10.y,x10.y}, sC2={x10.z,x10.z}, sC3={x10.w,x10.w};
        v2f sD0={x11.x,x11.x}, sD1={x11.y,x11.y}, sD2={x11.z,x11.z}, sD3={x11.w,x11.w};
        #pragma unroll
        for (int m = 0; m < MM; m++) {
            const v4f* PA = &Pl[(0*MM + m) * 4];
            const v4f* PB = &Pl[(1*MM + m) * 4];
            v4f a0=PA[0], a1=PA[1], a2=PA[2], a3=PA[3];
            v4f e0=PB[0], e1=PB[1], e2=PB[2], e3=PB[3];
            v2f tl, th, ul, uh;
            dotc(a0,a1,a2,a3, sA0,sA1,sA2,sA3, tl, th);
            dotc(e0,e1,e2,e3, sB0,sB1,sB2,sB3, ul, uh);
            alo[0][m] = tl*ul; ahi[0][m] = th*uh;
            dotc(a0,a1,a2,a3, sC0,sC1,sC2,sC3, tl, th);
            dotc(e0,e1,e2,e3, sD0,sD1,sD2,sD3, ul, uh);
            alo[1][m] = tl*ul; ahi[1][m] = th*uh;
        }
    }

    // ---- steps 1..18: node 20+j = (internal 19+j, leaf j+1) ----
    v4f xl0 = X4[b0 + 2], xl1 = X4[b1 + 2];
    #pragma unroll 1
    for (int j = 1; j < KINT; j++) {
        v4f nx0 = xl0, nx1 = xl1;
        if (j < KINT - 1) { nx0 = X4[b0 + j + 2]; nx1 = X4[b1 + j + 2]; }

        const v4f* PI = &Pl[(2*j) * MM * 4];
        const v4f* PL = PI + MM * 4;

        v2f x0s0={xl0.x,xl0.x}, x0s1={xl0.y,xl0.y}, x0s2={xl0.z,xl0.z}, x0s3={xl0.w,xl0.w};
        v2f x1s0={xl1.x,xl1.x}, x1s1={xl1.y,xl1.y}, x1s2={xl1.z,xl1.z}, x1s3={xl1.w,xl1.w};

        #pragma unroll
        for (int m = 0; m < MM; m++) {
            v4f ci0=PI[m*4+0], ci1=PI[m*4+1], ci2=PI[m*4+2], ci3=PI[m*4+3];
            v4f cl0=PL[m*4+0], cl1=PL[m*4+1], cl2=PL[m*4+2], cl3=PL[m*4+3];
            v2f tl, th, ul, uh;
            // site 0
            dotc(ci0,ci1,ci2,ci3,
                 (v2f){alo[0][m].x, alo[0][m].x}, (v2f){alo[0][m].y, alo[0][m].y},
                 (v2f){ahi[0][m].x, ahi[0][m].x}, (v2f){ahi[0][m].y, ahi[0][m].y},
                 tl, th);
            dotc(cl0,cl1,cl2,cl3, x0s0,x0s1,x0s2,x0s3, ul, uh);
            alo[0][m] = tl*ul; ahi[0][m] = th*uh;
            // site 1
            dotc(ci0,ci1,ci2,ci3,
                 (v2f){alo[1][m].x, alo[1][m].x}, (v2f){alo[1][m].y, alo[1][m].y},
                 (v2f){ahi[1][m].x, ahi[1][m].x}, (v2f){ahi[1][m].y, ahi[1][m].y},
                 tl, th);
            dotc(cl0,cl1,cl2,cl3, x1s0,x1s1,x1s2,x1s3, ul, uh);
            alo[1][m] = tl*ul; ahi[1][m] = th*uh;
        }
        xl0 = nx0; xl1 = nx1;
    }

    // ---- epilogue: out[i,m] = sum_c A[m][c] * pi[m][c] ----
    float r0[MM], r1[MM];
    #pragma unroll
    for (int m = 0; m < MM; m++) {
        v4f pim = Pl[P4 + m];
        v2f plo = (v2f){pim.x, pim.y}, phi = (v2f){pim.z, pim.w};
        v2f s0 = __builtin_elementwise_fma(ahi[0][m], phi, alo[0][m] * plo);
        v2f s1 = __builtin_elementwise_fma(ahi[1][m], phi, alo[1][m] * plo);
        r0[m] = s0.x + s0.y;
        r1[m] = s1.x + s1.y;
    }
    v4f* o4 = (v4f*)out;
    if (i0 < batch) {
        o4[(size_t)i0*2 + 0] = (v4f){r0[0], r0[1], r0[2], r0[3]};
        o4[(size_t)i0*2 + 1] = (v4f){r0[4], r0[5], r0[6], r0[7]};
    }
    if (i1 < batch) {
        o4[(size_t)i1*2 + 0] = (v4f){r1[0], r1[1], r1[2], r1[3]};
        o4[(size_t)i1*2 + 1] = (v4f){r1[4], r1[5], r1[6], r1[7]};
    }
}

// ---------------- launch ----------------

extern "C" void kernel_launch(void* const* d_in, const int* in_sizes, int n_in,
                              void* d_out, int out_size, void* d_ws, size_t ws_size,
                              hipStream_t stream)
{
    const float* X      = (const float*)d_in[0];
    const float* rates  = (const float*)d_in[1];
    const float* pi_inv = (const float*)d_in[2];
    const float* rho    = (const float*)d_in[3];
    const float* T      = (const float*)d_in[4];
    float* out = (float*)d_out;
    float* ws  = (float*)d_ws;

    int batch = in_sizes[0] / (NLEAF * SS);

    hipLaunchKernelGGL(setup_kernel, dim3(1), dim3(320), 0, stream,
                       rates, pi_inv, rho, T, ws);

    int grid = (batch + 255) / 256;   // 256 sites per 128-thread block
    hipLaunchKernelGGL(phylo_kernel, dim3(grid), dim3(128), 0, stream,
                       X, ws, out, batch);
}